// Round 1
// baseline (714.479 us; speedup 1.0000x reference)
//
#include <hip/hip_runtime.h>
#include <hip/hip_bf16.h>

#define SEQ   2048
#define DIMSZ 2048
#define NHEAD 16
#define HD    128
#define KDIM  2048

typedef __attribute__((ext_vector_type(8))) short bf16x8;
typedef __attribute__((ext_vector_type(4))) float f32x4;
typedef __attribute__((ext_vector_type(4))) short short4v;
typedef __attribute__((ext_vector_type(4))) float float4v;

__device__ __forceinline__ short f2bf(float f) {
    union { __hip_bfloat16 h; short s; } u;
    u.h = __float2bfloat16(f);
    return u.s;
}

__device__ __forceinline__ void gload_lds16(const void* g, void* l) {
    __builtin_amdgcn_global_load_lds(
        (const __attribute__((address_space(1))) void*)g,
        (__attribute__((address_space(3))) void*)l, 16, 0, 0);
}

// ---------------- fp32 -> bf16 elementwise convert ----------------
__global__ __launch_bounds__(256) void cvt_bf16(const float* __restrict__ in,
                                                short* __restrict__ out) {
    int i = (blockIdx.x * 256 + threadIdx.x) * 4;
    float4v v = *reinterpret_cast<const float4v*>(in + i);
    short4v o;
    o[0] = f2bf(v[0]); o[1] = f2bf(v[1]); o[2] = f2bf(v[2]); o[3] = f2bf(v[3]);
    *reinterpret_cast<short4v*>(out + i) = o;
}

// ---------------- fp32 [R][C] -> bf16 [C][R] transpose ----------------
__global__ __launch_bounds__(256) void transpose_cvt(const float* __restrict__ in,
                                                     short* __restrict__ out,
                                                     int R, int C) {
    __shared__ float tile[32][33];
    int c0 = blockIdx.x * 32, r0 = blockIdx.y * 32;
    int tx = threadIdx.x, ty = threadIdx.y;   // 32 x 8
#pragma unroll
    for (int i = 0; i < 32; i += 8)
        tile[ty + i][tx] = in[(long)(r0 + ty + i) * C + c0 + tx];
    __syncthreads();
#pragma unroll
    for (int i = 0; i < 32; i += 8)
        out[(long)(c0 + ty + i) * R + r0 + tx] = f2bf(tile[tx][ty + i]);
}

// ---------------- 128x128-tile bf16 GEMM, C = A[M,K] * Bt[N,K]^T + bias ----------------
// MODE 0: epilogue scatters bf16 into q_buf [bh][s][hd], k_buf [bh][s][hd], vt_buf [bh][hd][s]
// MODE 1: epilogue writes fp32 to outf [M][DIMSZ]
template <int MODE>
__global__ __launch_bounds__(256) void gemm_bt(const short* __restrict__ A,
                                               const short* __restrict__ Bt,
                                               const float* __restrict__ bias,
                                               float* __restrict__ outf,
                                               short* __restrict__ q_buf,
                                               short* __restrict__ k_buf,
                                               short* __restrict__ vt_buf) {
    __shared__ short Alds[128 * 64];
    __shared__ short Blds[128 * 64];
    const int tid = threadIdx.x;
    const int wave = tid >> 6, lane = tid & 63;
    const int lr = lane & 15, lg = lane >> 4;
    const int m0 = blockIdx.y * 128, n0 = blockIdx.x * 128;
    const int wr = (wave >> 1) * 64, wc = (wave & 1) * 64;
    const short* Ab = A + (long)m0 * KDIM;
    const short* Bb = Bt + (long)n0 * KDIM;
    const int srow = tid >> 3;        // staging row within 32-row group
    const int sch = (tid & 7) * 8;    // staging k-offset (8 bf16 = 16B chunks)

    f32x4 acc[4][4] = {};

    for (int kt = 0; kt < KDIM; kt += 64) {
#pragma unroll
        for (int i = 0; i < 4; ++i) {
            gload_lds16(Ab + (long)(i * 32 + srow) * KDIM + kt + sch,
                        &Alds[(i * 256 + wave * 64) * 8]);
            gload_lds16(Bb + (long)(i * 32 + srow) * KDIM + kt + sch,
                        &Blds[(i * 256 + wave * 64) * 8]);
        }
        __syncthreads();
#pragma unroll
        for (int kk = 0; kk < 2; ++kk) {
            bf16x8 af[4], bfr[4];
#pragma unroll
            for (int mi = 0; mi < 4; ++mi)
                af[mi] = *reinterpret_cast<const bf16x8*>(
                    &Alds[(wr + mi * 16 + lr) * 64 + kk * 32 + lg * 8]);
#pragma unroll
            for (int ni = 0; ni < 4; ++ni)
                bfr[ni] = *reinterpret_cast<const bf16x8*>(
                    &Blds[(wc + ni * 16 + lr) * 64 + kk * 32 + lg * 8]);
#pragma unroll
            for (int mi = 0; mi < 4; ++mi)
#pragma unroll
                for (int ni = 0; ni < 4; ++ni)
                    acc[mi][ni] = __builtin_amdgcn_mfma_f32_16x16x32_bf16(
                        af[mi], bfr[ni], acc[mi][ni], 0, 0, 0);
        }
        __syncthreads();
    }

#pragma unroll
    for (int mi = 0; mi < 4; ++mi) {
#pragma unroll
        for (int ni = 0; ni < 4; ++ni) {
            int col = n0 + wc + ni * 16 + lr;
            float bv = bias[col];
#pragma unroll
            for (int j = 0; j < 4; ++j) {
                int row = m0 + wr + mi * 16 + lg * 4 + j;
                float v = acc[mi][ni][j] + bv;
                if (MODE == 0) {
                    int h = col / (3 * HD);
                    int jj = col - h * (3 * HD);
                    int b = row >> 11, s = row & 2047;
                    int bh = b * NHEAD + h;
                    short sv = f2bf(v);
                    if (jj < HD)
                        q_buf[(bh * SEQ + s) * HD + jj] = sv;
                    else if (jj < 2 * HD)
                        k_buf[(bh * SEQ + s) * HD + (jj - HD)] = sv;
                    else
                        vt_buf[(bh * HD + (jj - 2 * HD)) * SEQ + s] = sv;
                } else {
                    outf[(long)row * DIMSZ + col] = v;
                }
            }
        }
    }
}

// ---------------- causal flash attention ----------------
// grid: (B*NHEAD)*32 blocks; block = 4 waves; wave handles 16 q rows.
// q_buf/k_buf: [bh][s][hd] bf16 ; vt_buf: [bh][hd][s] bf16 ; ao: [b][s][h*HD] bf16
__global__ __launch_bounds__(256) void attn_kernel(const short* __restrict__ q_buf,
                                                   const short* __restrict__ k_buf,
                                                   const short* __restrict__ vt_buf,
                                                   short* __restrict__ ao) {
    __shared__ short p_lds[4][16 * 56];   // per-wave 16x32 P tile, row stride 56 (112B, 16B-aligned)
    const int tid = threadIdx.x;
    const int wave = tid >> 6, lane = tid & 63;
    const int lr = lane & 15, lg = lane >> 4;
    const int bh = blockIdx.x >> 5, qt = blockIdx.x & 31;
    const int b = bh >> 4, h = bh & 15;
    const int qbase = qt * 64 + wave * 16;
    const float scale = 0.08838834764831845f;   // 1/sqrt(128)

    bf16x8 qf[4];
    const short* qrow = q_buf + (bh * SEQ + qbase + lr) * HD;
#pragma unroll
    for (int c = 0; c < 4; ++c)
        qf[c] = *reinterpret_cast<const bf16x8*>(qrow + c * 32 + lg * 8);

    f32x4 o_acc[8] = {};
    float mrow[4] = {-__builtin_inff(), -__builtin_inff(), -__builtin_inff(), -__builtin_inff()};
    float lrow[4] = {0.f, 0.f, 0.f, 0.f};
    short* pl = &p_lds[wave][0];

    const int my_end = qbase + 16;   // last kv row this wave needs is qbase+15
    for (int kv0 = 0; kv0 < my_end; kv0 += 32) {
        // ---- scores: S[16q][32kv] via 2 column tiles
        f32x4 sc0 = {0.f, 0.f, 0.f, 0.f}, sc1 = {0.f, 0.f, 0.f, 0.f};
        const short* krow = k_buf + (bh * SEQ + kv0 + lr) * HD;
#pragma unroll
        for (int c = 0; c < 4; ++c) {
            bf16x8 k0 = *reinterpret_cast<const bf16x8*>(krow + c * 32 + lg * 8);
            bf16x8 k1 = *reinterpret_cast<const bf16x8*>(krow + 16 * HD + c * 32 + lg * 8);
            sc0 = __builtin_amdgcn_mfma_f32_16x16x32_bf16(qf[c], k0, sc0, 0, 0, 0);
            sc1 = __builtin_amdgcn_mfma_f32_16x16x32_bf16(qf[c], k1, sc1, 0, 0, 0);
        }
        // ---- mask + scale; lane holds rows lg*4+j, col kv0 + {0,16} + lr
        float pv0[4], pv1[4], pm[4];
#pragma unroll
        for (int j = 0; j < 4; ++j) {
            int qg = qbase + lg * 4 + j;
            float v0 = sc0[j] * scale;
            float v1 = sc1[j] * scale;
            if (kv0 + lr > qg) v0 = -__builtin_inff();
            if (kv0 + 16 + lr > qg) v1 = -__builtin_inff();
            pv0[j] = v0; pv1[j] = v1;
            pm[j] = fmaxf(v0, v1);
        }
#pragma unroll
        for (int m = 1; m < 16; m <<= 1)
#pragma unroll
            for (int j = 0; j < 4; ++j)
                pm[j] = fmaxf(pm[j], __shfl_xor(pm[j], m, 64));
        float alpha[4], psum[4];
#pragma unroll
        for (int j = 0; j < 4; ++j) {
            float mn = fmaxf(mrow[j], pm[j]);
            alpha[j] = __expf(mrow[j] - mn);
            mrow[j] = mn;
            float p0 = __expf(pv0[j] - mn);
            float p1 = __expf(pv1[j] - mn);
            pv0[j] = p0; pv1[j] = p1;
            psum[j] = p0 + p1;
        }
#pragma unroll
        for (int m = 1; m < 16; m <<= 1)
#pragma unroll
            for (int j = 0; j < 4; ++j)
                psum[j] += __shfl_xor(psum[j], m, 64);
#pragma unroll
        for (int j = 0; j < 4; ++j)
            lrow[j] = lrow[j] * alpha[j] + psum[j];
#pragma unroll
        for (int n = 0; n < 8; ++n)
#pragma unroll
            for (int j = 0; j < 4; ++j)
                o_acc[n][j] *= alpha[j];
        // ---- transpose P through per-wave LDS slice (D-layout -> A-frag layout)
#pragma unroll
        for (int j = 0; j < 4; ++j) {
            pl[(lg * 4 + j) * 56 + lr] = f2bf(pv0[j]);
            pl[(lg * 4 + j) * 56 + 16 + lr] = f2bf(pv1[j]);
        }
        bf16x8 paf = *reinterpret_cast<const bf16x8*>(&pl[lr * 56 + lg * 8]);
        // ---- PV: O[16q][128hd] += P[16][32] x V[32][128]
        const short* vcol = vt_buf + (bh * HD + lr) * SEQ + kv0 + lg * 8;
#pragma unroll
        for (int n = 0; n < 8; ++n) {
            bf16x8 vf = *reinterpret_cast<const bf16x8*>(vcol + n * 16 * SEQ);
            o_acc[n] = __builtin_amdgcn_mfma_f32_16x16x32_bf16(paf, vf, o_acc[n], 0, 0, 0);
        }
    }

    float inv[4];
#pragma unroll
    for (int j = 0; j < 4; ++j) inv[j] = 1.0f / lrow[j];
    short* aor = ao + (b * SEQ + qbase) * DIMSZ + h * HD;
#pragma unroll
    for (int n = 0; n < 8; ++n)
#pragma unroll
        for (int j = 0; j < 4; ++j)
            aor[(lg * 4 + j) * DIMSZ + n * 16 + lr] = f2bf(o_acc[n][j] * inv[j]);
}

// ---------------- launcher ----------------
extern "C" void kernel_launch(void* const* d_in, const int* in_sizes, int n_in,
                              void* d_out, int out_size, void* d_ws, size_t ws_size,
                              hipStream_t stream) {
    const float* x     = (const float*)d_in[0];
    // d_in[1] is the causal mask; semantics are hardcoded (tril), not read.
    const float* W_qkv = (const float*)d_in[2];
    const float* b_qkv = (const float*)d_in[3];
    const float* W_out = (const float*)d_in[4];
    const float* b_out = (const float*)d_in[5];
    float* out = (float*)d_out;

    char* ws = (char*)d_ws;
    short* x_bf   = (short*)ws;                          // 16 MB  [4096][2048] bf16
    short* wqkv_t = (short*)(ws + (size_t)16 * 1048576); // 24 MB  [6144][2048] bf16
    short* wout_t = (short*)(ws + (size_t)40 * 1048576); //  8 MB  [2048][2048] bf16
    short* q_buf  = (short*)(ws + (size_t)48 * 1048576); // 16 MB  [32][2048][128]
    short* k_buf  = (short*)(ws + (size_t)64 * 1048576); // 16 MB
    short* vt_buf = (short*)(ws + (size_t)80 * 1048576); // 16 MB  [32][128][2048]
    short* ao     = x_bf;  // x_bf is dead after gemm1; reuse for attention output

    cvt_bf16<<<8192, 256, 0, stream>>>(x, x_bf);
    transpose_cvt<<<dim3(192, 64), dim3(32, 8), 0, stream>>>(W_qkv, wqkv_t, 2048, 6144);
    transpose_cvt<<<dim3(64, 64), dim3(32, 8), 0, stream>>>(W_out, wout_t, 2048, 2048);
    gemm_bt<0><<<dim3(48, 32), 256, 0, stream>>>(x_bf, wqkv_t, b_qkv, nullptr,
                                                 q_buf, k_buf, vt_buf);
    attn_kernel<<<1024, 256, 0, stream>>>(q_buf, k_buf, vt_buf, ao);
    gemm_bt<1><<<dim3(16, 32), 256, 0, stream>>>(ao, wout_t, b_out, out,
                                                 nullptr, nullptr, nullptr);
}

// Round 2
// 339.917 us; speedup vs baseline: 2.1019x; 2.1019x over previous
//
#include <hip/hip_runtime.h>
#include <hip/hip_bf16.h>

#define SEQ   2048
#define DIMSZ 2048
#define NHEAD 16
#define HD    128
#define KDIM  2048

typedef __attribute__((ext_vector_type(8))) short bf16x8;
typedef __attribute__((ext_vector_type(4))) float f32x4;
typedef __attribute__((ext_vector_type(4))) short short4v;
typedef __attribute__((ext_vector_type(4))) float float4v;

__device__ __forceinline__ short f2bf(float f) {
    union { __hip_bfloat16 h; short s; } u;
    u.h = __float2bfloat16(f);
    return u.s;
}

__device__ __forceinline__ void gload_lds16(const void* g, void* l) {
    __builtin_amdgcn_global_load_lds(
        (const __attribute__((address_space(1))) void*)g,
        (__attribute__((address_space(3))) void*)l, 16, 0, 0);
}

// ---------------- fp32 -> bf16 elementwise convert ----------------
__global__ __launch_bounds__(256) void cvt_bf16(const float* __restrict__ in,
                                                short* __restrict__ out) {
    int i = (blockIdx.x * 256 + threadIdx.x) * 4;
    float4v v = *reinterpret_cast<const float4v*>(in + i);
    short4v o;
    o[0] = f2bf(v[0]); o[1] = f2bf(v[1]); o[2] = f2bf(v[2]); o[3] = f2bf(v[3]);
    *reinterpret_cast<short4v*>(out + i) = o;
}

// ---------------- fp32 [R][C] -> bf16 [C][R] transpose ----------------
__global__ __launch_bounds__(256) void transpose_cvt(const float* __restrict__ in,
                                                     short* __restrict__ out,
                                                     int R, int C) {
    __shared__ float tile[32][33];
    int c0 = blockIdx.x * 32, r0 = blockIdx.y * 32;
    int tx = threadIdx.x, ty = threadIdx.y;   // 32 x 8
#pragma unroll
    for (int i = 0; i < 32; i += 8)
        tile[ty + i][tx] = in[(long)(r0 + ty + i) * C + c0 + tx];
    __syncthreads();
#pragma unroll
    for (int i = 0; i < 32; i += 8)
        out[(long)(c0 + ty + i) * R + r0 + tx] = f2bf(tile[tx][ty + i]);
}

// ---------------- 128x128-tile bf16 GEMM, C = A[M,K] * Bt[N,K]^T + bias ----------------
template <int MODE>
__global__ __launch_bounds__(256) void gemm_bt(const short* __restrict__ A,
                                               const short* __restrict__ Bt,
                                               const float* __restrict__ bias,
                                               float* __restrict__ outf,
                                               short* __restrict__ q_buf,
                                               short* __restrict__ k_buf,
                                               short* __restrict__ vt_buf) {
    __shared__ short Alds[128 * 64];
    __shared__ short Blds[128 * 64];
    const int tid = threadIdx.x;
    const int wave = tid >> 6, lane = tid & 63;
    const int lr = lane & 15, lg = lane >> 4;
    const int m0 = blockIdx.y * 128, n0 = blockIdx.x * 128;
    const int wr = (wave >> 1) * 64, wc = (wave & 1) * 64;
    const short* Ab = A + (long)m0 * KDIM;
    const short* Bb = Bt + (long)n0 * KDIM;
    const int srow = tid >> 3;
    const int sch = (tid & 7) * 8;

    f32x4 acc[4][4] = {};

    for (int kt = 0; kt < KDIM; kt += 64) {
#pragma unroll
        for (int i = 0; i < 4; ++i) {
            gload_lds16(Ab + (long)(i * 32 + srow) * KDIM + kt + sch,
                        &Alds[(i * 256 + wave * 64) * 8]);
            gload_lds16(Bb + (long)(i * 32 + srow) * KDIM + kt + sch,
                        &Blds[(i * 256 + wave * 64) * 8]);
        }
        __syncthreads();
#pragma unroll
        for (int kk = 0; kk < 2; ++kk) {
            bf16x8 af[4], bfr[4];
#pragma unroll
            for (int mi = 0; mi < 4; ++mi)
                af[mi] = *reinterpret_cast<const bf16x8*>(
                    &Alds[(wr + mi * 16 + lr) * 64 + kk * 32 + lg * 8]);
#pragma unroll
            for (int ni = 0; ni < 4; ++ni)
                bfr[ni] = *reinterpret_cast<const bf16x8*>(
                    &Blds[(wc + ni * 16 + lr) * 64 + kk * 32 + lg * 8]);
#pragma unroll
            for (int mi = 0; mi < 4; ++mi)
#pragma unroll
                for (int ni = 0; ni < 4; ++ni)
                    acc[mi][ni] = __builtin_amdgcn_mfma_f32_16x16x32_bf16(
                        af[mi], bfr[ni], acc[mi][ni], 0, 0, 0);
        }
        __syncthreads();
    }

#pragma unroll
    for (int mi = 0; mi < 4; ++mi) {
#pragma unroll
        for (int ni = 0; ni < 4; ++ni) {
            int col = n0 + wc + ni * 16 + lr;
            float bv = bias[col];
#pragma unroll
            for (int j = 0; j < 4; ++j) {
                int row = m0 + wr + mi * 16 + lg * 4 + j;
                float v = acc[mi][ni][j] + bv;
                if (MODE == 0) {
                    int h = col / (3 * HD);
                    int jj = col - h * (3 * HD);
                    int b = row >> 11, s = row & 2047;
                    int bh = b * NHEAD + h;
                    short sv = f2bf(v);
                    if (jj < HD)
                        q_buf[(bh * SEQ + s) * HD + jj] = sv;
                    else if (jj < 2 * HD)
                        k_buf[(bh * SEQ + s) * HD + (jj - HD)] = sv;
                    else
                        vt_buf[(bh * HD + (jj - 2 * HD)) * SEQ + s] = sv;
                } else {
                    outf[(long)row * DIMSZ + col] = v;
                }
            }
        }
    }
}

// ---------------- causal flash attention, LDS-staged double-buffered ----------------
// grid: 512 blocks = 16 q-tiles (heavy-first) x 32 bh; block = 4 waves; wave = 32 q rows.
// KVBLK = 64.  K staged [64][128] bf16, V staged transposed [128][64] bf16, both
// XOR-swizzled (chunk ^= (row&7)) via pre-swizzled global_load_lds source addresses.
__global__ __launch_bounds__(256, 2) void attn_kernel(const short* __restrict__ q_buf,
                                                      const short* __restrict__ k_buf,
                                                      const short* __restrict__ vt_buf,
                                                      short* __restrict__ ao) {
    __shared__ __align__(16) short Klds[2][64 * 128];
    __shared__ __align__(16) short Vlds[2][128 * 64];
    __shared__ __align__(16) short Plds[4][32 * 64];
    const int tid = threadIdx.x;
    const int wave = tid >> 6, lane = tid & 63;
    const int lr = lane & 15, lg = lane >> 4;
    const int bx = blockIdx.x;
    const int qt = 15 - (bx >> 5);      // heavy q-tiles dispatched first
    const int bh = bx & 31;
    const int b = bh >> 4, h = bh & 15;
    const int qbase = qt * 128 + wave * 32;
    const float scale = 0.08838834764831845f;   // 1/sqrt(128)

    // ---- Q fragments: 32 rows per wave, kept in registers
    bf16x8 qf[2][4];
    {
        const short* qrow = q_buf + ((long)(bh * SEQ + qbase + lr)) * HD;
#pragma unroll
        for (int mi = 0; mi < 2; ++mi)
#pragma unroll
            for (int c = 0; c < 4; ++c)
                qf[mi][c] = *reinterpret_cast<const bf16x8*>(
                    qrow + mi * 16 * HD + c * 32 + lg * 8);
    }
    asm volatile("s_waitcnt vmcnt(0)" ::: "memory");  // drain Q so vmcnt(8) below is exact

    // ---- per-lane staging source offsets (pre-swizzled global addresses)
    const char* kbase = (const char*)(k_buf + (long)bh * SEQ * HD);
    const char* vbase = (const char*)(vt_buf + (long)bh * HD * SEQ);
    const int krow_l = wave * 4 + (lane >> 4);                        // row within 16-row issue
    const int kcol_l = ((lane & 15) * 16) ^ ((krow_l & 7) << 4);
    const int vrow_l = wave * 8 + (lane >> 3);                        // row within 32-row issue
    const int vcol_l = ((lane & 7) * 16) ^ ((vrow_l & 7) << 4);

    const int nt = 2 * (qt + 1);
    auto stage = [&](int bufi, int t) {
        const char* ks = kbase + (long)t * 16384 + (long)krow_l * 256 + kcol_l;
        const char* vs = vbase + (long)t * 128 + (long)vrow_l * (SEQ * 2) + vcol_l;
        short* kd = &Klds[bufi][wave * 512];
        short* vd = &Vlds[bufi][wave * 512];
#pragma unroll
        for (int i = 0; i < 4; ++i) {
            gload_lds16(ks + i * 4096, kd + i * 2048);
            gload_lds16(vs + (long)i * 32 * SEQ * 2, vd + i * 2048);
        }
    };

    f32x4 o_acc[2][8] = {};
    float mrow[2][4], lrow[2][4];
#pragma unroll
    for (int mi = 0; mi < 2; ++mi)
#pragma unroll
        for (int j = 0; j < 4; ++j) { mrow[mi][j] = -1e30f; lrow[mi][j] = 0.f; }
    short* pw = &Plds[wave][0];

    stage(0, 0);
    for (int t = 0; t < nt; ++t) {
        const int cur = t & 1;
        if (t + 1 < nt) {
            stage(cur ^ 1, t + 1);
            asm volatile("s_waitcnt vmcnt(8)" ::: "memory");  // cur's 8 loads done, next's in flight
        } else {
            asm volatile("s_waitcnt vmcnt(0)" ::: "memory");
        }
        __builtin_amdgcn_s_barrier();
        __builtin_amdgcn_sched_barrier(0);

        const int kv0 = t * 64;
        if (kv0 <= qbase + 31) {              // skip fully-masked tiles (barriers stay aligned)
            // ---- QK^T : S[32q][64kv]
            f32x4 sc[2][4] = {};
            const short* kl = &Klds[cur][0];
#pragma unroll
            for (int c = 0; c < 4; ++c) {
                bf16x8 kf[4];
#pragma unroll
                for (int ni = 0; ni < 4; ++ni)
                    kf[ni] = *reinterpret_cast<const bf16x8*>(
                        kl + (((ni * 16 + lr) * 256 +
                               ((c * 64 + lg * 16) ^ ((lr & 7) << 4))) >> 1));
#pragma unroll
                for (int mi = 0; mi < 2; ++mi)
#pragma unroll
                    for (int ni = 0; ni < 4; ++ni)
                        sc[mi][ni] = __builtin_amdgcn_mfma_f32_16x16x32_bf16(
                            qf[mi][c], kf[ni], sc[mi][ni], 0, 0, 0);
            }
            // ---- online softmax (rows: mi*16+lg*4+j ; cols: ni*16+lr)
            const bool full = (kv0 + 63) <= qbase;
            float pv[2][4][4], pm[2][4];
#pragma unroll
            for (int mi = 0; mi < 2; ++mi)
#pragma unroll
                for (int j = 0; j < 4; ++j) {
                    float mx = -3e38f;
#pragma unroll
                    for (int ni = 0; ni < 4; ++ni) {
                        float v = sc[mi][ni][j] * scale;
                        if (!full) {
                            int qg = qbase + mi * 16 + lg * 4 + j;
                            if (kv0 + ni * 16 + lr > qg) v = -1e9f;
                        }
                        pv[mi][ni][j] = v;
                        mx = fmaxf(mx, v);
                    }
                    pm[mi][j] = mx;
                }
#pragma unroll
            for (int m = 1; m < 16; m <<= 1)
#pragma unroll
                for (int mi = 0; mi < 2; ++mi)
#pragma unroll
                    for (int j = 0; j < 4; ++j)
                        pm[mi][j] = fmaxf(pm[mi][j], __shfl_xor(pm[mi][j], m, 64));
            float alpha[2][4], psum[2][4];
#pragma unroll
            for (int mi = 0; mi < 2; ++mi)
#pragma unroll
                for (int j = 0; j < 4; ++j) {
                    float mn = fmaxf(mrow[mi][j], pm[mi][j]);
                    alpha[mi][j] = __expf(mrow[mi][j] - mn);
                    mrow[mi][j] = mn;
                    psum[mi][j] = 0.f;
                }
#pragma unroll
            for (int mi = 0; mi < 2; ++mi)
#pragma unroll
                for (int ni = 0; ni < 4; ++ni)
#pragma unroll
                    for (int j = 0; j < 4; ++j) {
                        float p = __expf(pv[mi][ni][j] - mrow[mi][j]);
                        pv[mi][ni][j] = p;
                        psum[mi][j] += p;
                    }
#pragma unroll
            for (int m = 1; m < 16; m <<= 1)
#pragma unroll
                for (int mi = 0; mi < 2; ++mi)
#pragma unroll
                    for (int j = 0; j < 4; ++j)
                        psum[mi][j] += __shfl_xor(psum[mi][j], m, 64);
#pragma unroll
            for (int mi = 0; mi < 2; ++mi)
#pragma unroll
                for (int j = 0; j < 4; ++j)
                    lrow[mi][j] = lrow[mi][j] * alpha[mi][j] + psum[mi][j];
#pragma unroll
            for (int mi = 0; mi < 2; ++mi)
#pragma unroll
                for (int n = 0; n < 8; ++n)
#pragma unroll
                    for (int j = 0; j < 4; ++j)
                        o_acc[mi][n][j] *= alpha[mi][j];
            // ---- P -> LDS (swizzled), per-wave private
#pragma unroll
            for (int mi = 0; mi < 2; ++mi)
#pragma unroll
                for (int ni = 0; ni < 4; ++ni)
#pragma unroll
                    for (int j = 0; j < 4; ++j) {
                        int row = mi * 16 + lg * 4 + j;
                        int cb = (ni * 32 + lr * 2) ^ ((row & 7) << 4);
                        pw[(row * 128 + cb) >> 1] = f2bf(pv[mi][ni][j]);
                    }
            // ---- PV : O[32q][128hd] += P[32][64] x V[64][128]
            const short* vl = &Vlds[cur][0];
#pragma unroll
            for (int kc = 0; kc < 2; ++kc) {
                bf16x8 pa[2];
#pragma unroll
                for (int mi = 0; mi < 2; ++mi)
                    pa[mi] = *reinterpret_cast<const bf16x8*>(
                        pw + (((mi * 16 + lr) * 128 +
                               ((kc * 64 + lg * 16) ^ ((lr & 7) << 4))) >> 1));
#pragma unroll
                for (int n = 0; n < 8; ++n) {
                    bf16x8 vf = *reinterpret_cast<const bf16x8*>(
                        vl + (((n * 16 + lr) * 128 +
                               ((kc * 64 + lg * 16) ^ ((lr & 7) << 4))) >> 1));
#pragma unroll
                    for (int mi = 0; mi < 2; ++mi)
                        o_acc[mi][n] = __builtin_amdgcn_mfma_f32_16x16x32_bf16(
                            pa[mi], vf, o_acc[mi][n], 0, 0, 0);
                }
            }
        }
        __builtin_amdgcn_s_barrier();
    }

    float inv[2][4];
#pragma unroll
    for (int mi = 0; mi < 2; ++mi)
#pragma unroll
        for (int j = 0; j < 4; ++j) inv[mi][j] = 1.0f / lrow[mi][j];
    short* aor = ao + ((long)(b * SEQ + qbase) * DIMSZ + h * HD);
#pragma unroll
    for (int mi = 0; mi < 2; ++mi)
#pragma unroll
        for (int n = 0; n < 8; ++n)
#pragma unroll
            for (int j = 0; j < 4; ++j)
                aor[(mi * 16 + lg * 4 + j) * DIMSZ + n * 16 + lr] =
                    f2bf(o_acc[mi][n][j] * inv[mi][j]);
}

// ---------------- launcher ----------------
extern "C" void kernel_launch(void* const* d_in, const int* in_sizes, int n_in,
                              void* d_out, int out_size, void* d_ws, size_t ws_size,
                              hipStream_t stream) {
    const float* x     = (const float*)d_in[0];
    // d_in[1] is the causal mask; semantics hardcoded (tril), not read.
    const float* W_qkv = (const float*)d_in[2];
    const float* b_qkv = (const float*)d_in[3];
    const float* W_out = (const float*)d_in[4];
    const float* b_out = (const float*)d_in[5];
    float* out = (float*)d_out;

    char* ws = (char*)d_ws;
    short* x_bf   = (short*)ws;                          // 16 MB
    short* wqkv_t = (short*)(ws + (size_t)16 * 1048576); // 24 MB
    short* wout_t = (short*)(ws + (size_t)40 * 1048576); //  8 MB
    short* q_buf  = (short*)(ws + (size_t)48 * 1048576); // 16 MB
    short* k_buf  = (short*)(ws + (size_t)64 * 1048576); // 16 MB
    short* vt_buf = (short*)(ws + (size_t)80 * 1048576); // 16 MB
    short* ao     = x_bf;  // x_bf dead after gemm1; reuse for attention output

    cvt_bf16<<<8192, 256, 0, stream>>>(x, x_bf);
    transpose_cvt<<<dim3(192, 64), dim3(32, 8), 0, stream>>>(W_qkv, wqkv_t, 2048, 6144);
    transpose_cvt<<<dim3(64, 64), dim3(32, 8), 0, stream>>>(W_out, wout_t, 2048, 2048);
    gemm_bt<0><<<dim3(48, 32), 256, 0, stream>>>(x_bf, wqkv_t, b_qkv, nullptr,
                                                 q_buf, k_buf, vt_buf);
    attn_kernel<<<512, 256, 0, stream>>>(q_buf, k_buf, vt_buf, ao);
    gemm_bt<1><<<dim3(16, 32), 256, 0, stream>>>(ao, wout_t, b_out, out,
                                                 nullptr, nullptr, nullptr);
}